// Round 24
// baseline (991.130 us; speedup 1.0000x reference)
//
#include <hip/hip_runtime.h>
#include <hip/hip_bf16.h>
#include <math.h>

#define NN   10000
#define EE   160000
#define CC   128
#define RBFD 20
#define HIDD 32
#define WND  384
#define MROW 1152   // 9*128 accumulator row: [m=0..8][c=0..127]
#define EPB  64     // edges per block
#define ET   4      // edges per weight tile

typedef _Float16 half2_t __attribute__((ext_vector_type(2)));

__device__ __forceinline__ half2_t u2h(unsigned int u)
{
    union { unsigned int u; half2_t h; } c; c.u = u; return c.h;
}
__device__ __forceinline__ unsigned int pack_h2(float a, float b)
{
    union { half2_t h; unsigned int u; } c;
    c.h.x = (_Float16)a; c.h.y = (_Float16)b; return c.u;
}

// Static device buffers. g_accu: starts zero (.bss); each call accumulates,
// lin2 re-zeroes after reading -> invariant "zero at call entry" holds.
__device__ __align__(16) float g_proj[(size_t)NN * 64];   // 2.6 MB
__device__ __align__(16) float g_accu[(size_t)NN * MROW]; // 46 MB
__device__ __align__(16) uint4 g_wp[3 * 16 * 64];         // 48 KB packed f16 weights
__device__ int g_deg[NN];
__device__ int g_offs[NN + 1];
__device__ int g_rel[EE];
__device__ int g_ord[EE];   // sorted row -> original edge

__device__ __forceinline__ float silu_f(float x) { return x / (1.f + __expf(-x)); }

// Pack MLP2 weights to f16 pairs + zero g_deg. Layout [sec][kind][q][lane].
__global__ __launch_bounds__(192) void pack_kernel(
    const float* __restrict__ Ws2, const float* __restrict__ Wr2)
{
    int tid = threadIdx.x;          // 192 = 3 sec x 64 lanes
    for (int i = tid; i < NN; i += 192) g_deg[i] = 0;
    int sec = tid >> 6, l = tid & 63;
    int c0 = sec * 128 + 2 * l;
    #pragma unroll
    for (int q = 0; q < 4; ++q) {
        unsigned int w0[4], w1[4], r0[4], r1[4];
        #pragma unroll
        for (int i = 0; i < 4; ++i) {
            int p = 4 * q + i;
            int b0 = (2 * p) * WND + c0;
            int b1 = (2 * p + 1) * WND + c0;
            w0[i] = pack_h2(Ws2[b0],     Ws2[b1]);
            w1[i] = pack_h2(Ws2[b0 + 1], Ws2[b1 + 1]);
            r0[i] = pack_h2(Wr2[b0],     Wr2[b1]);
            r1[i] = pack_h2(Wr2[b0 + 1], Wr2[b1 + 1]);
        }
        g_wp[((sec * 16 + 0 * 4 + q) * 64) + l] = make_uint4(w0[0], w0[1], w0[2], w0[3]);
        g_wp[((sec * 16 + 1 * 4 + q) * 64) + l] = make_uint4(w1[0], w1[1], w1[2], w1[3]);
        g_wp[((sec * 16 + 2 * 4 + q) * 64) + l] = make_uint4(r0[0], r0[1], r0[2], r0[3]);
        g_wp[((sec * 16 + 3 * 4 + q) * 64) + l] = make_uint4(r1[0], r1[1], r1[2], r1[3]);
    }
}

__global__ __launch_bounds__(256) void hist_kernel(const int* __restrict__ edge_index)
{
    int e = blockIdx.x * 256 + threadIdx.x;
    if (e < EE) g_rel[e] = atomicAdd(&g_deg[edge_index[e]], 1);
}

// Blocked scan: 256 threads x 40 items, one block.
__global__ __launch_bounds__(256) void scan_kernel()
{
    __shared__ int sP[256];
    int t = threadIdx.x;
    int lo = t * 40, hi = min(lo + 40, NN);
    int sum = 0;
    for (int i = lo; i < hi; ++i) sum += g_deg[i];
    sP[t] = sum;
    __syncthreads();
    for (int off = 1; off < 256; off <<= 1) {
        int v = (t >= off) ? sP[t - off] : 0;
        __syncthreads();
        sP[t] += v;
        __syncthreads();
    }
    int run = sP[t] - sum;   // exclusive prefix
    if (t == 0) g_offs[0] = 0;
    for (int i = lo; i < hi; ++i) { run += g_deg[i]; g_offs[i + 1] = run; }
}

// MLP1 halves + edge permutation (grid is exactly EE threads).
__global__ __launch_bounds__(256) void proj_kernel(
    const float* __restrict__ nf,
    const float* __restrict__ Ws1, const float* __restrict__ bs1,
    const int* __restrict__ edge_index)
{
    __shared__ float sX[16][132];

    int tid = threadIdx.x;
    int nb = blockIdx.x * 16;       // grid exact: NN/16 = 625

    {
        int eg = blockIdx.x * 256 + tid;
        g_ord[g_offs[edge_index[eg]] + g_rel[eg]] = eg;
    }

    #pragma unroll
    for (int i = tid; i < 512; i += 256) {
        int n = i >> 5, k4 = i & 31;
        float4 v = reinterpret_cast<const float4*>(nf + (size_t)(nb + n) * CC)[k4];
        sX[n][k4 * 4 + 0] = v.x;
        sX[n][k4 * 4 + 1] = v.y;
        sX[n][k4 * 4 + 2] = v.z;
        sX[n][k4 * 4 + 3] = v.w;
    }
    __syncthreads();

    int nl = tid >> 4;
    int qd = tid & 15;
    int j0 = (qd & 7) * 4;
    int rbase = (qd >= 8) ? CC : 0;

    float4 acc;
    if (qd < 8) acc = *reinterpret_cast<const float4*>(&bs1[j0]);
    else        acc = make_float4(0.f, 0.f, 0.f, 0.f);

    const float* wb = Ws1 + (size_t)rbase * HIDD + j0;
    #pragma unroll 4
    for (int k = 0; k < CC; ++k) {
        float f = sX[nl][k];
        float4 w = *reinterpret_cast<const float4*>(wb + (size_t)k * HIDD);
        acc.x = fmaf(f, w.x, acc.x);
        acc.y = fmaf(f, w.y, acc.y);
        acc.z = fmaf(f, w.z, acc.z);
        acc.w = fmaf(f, w.w, acc.w);
    }

    float* o = g_proj + (size_t)(nb + nl) * 64 + ((qd >= 8) ? HIDD : 0) + j0;
    *reinterpret_cast<float4*>(o) = acc;
}

// One 128-col section over EPB sorted edges, 4-edge weight tiles: per q-step
// load ONE q's 4 uint4 (16 u32 live only inside loop) and apply to 4 edges
// -> 4x fewer weight VMEM than per-edge remat. h broadcast b128 from LDS;
// per-segment register accumulation; wave-coalesced atomic flushes.
template<int K, int YB, int MOFF>
__device__ __forceinline__ void section_pass(
    int sec, int l,
    const float2* __restrict__ nf2,
    const float* __restrict__ bs2, const float* __restrict__ br2,
    const unsigned int (*__restrict__ sH)[36], const float (*__restrict__ sY)[9],
    const int* __restrict__ sSrc, const int* __restrict__ sDst)
{
    const uint4* wt = g_wp + (size_t)sec * 16 * 64 + l;   // stride 64 per slot
    float2 bsv = *reinterpret_cast<const float2*>(&bs2[sec * 128 + 2 * l]);
    float2 brv = *reinterpret_cast<const float2*>(&br2[sec * 128 + 2 * l]);

    float racc0[K], racc1[K];
    #pragma unroll
    for (int k = 0; k < K; ++k) { racc0[k] = 0.f; racc1[k] = 0.f; }
    int cur = sSrc[0];

    #pragma unroll 1
    for (int et = 0; et < EPB / ET; ++et) {
        // prefetch xj for this tile (independent loads, in flight during dot2s)
        float2 xjv[ET];
        #pragma unroll
        for (int e4 = 0; e4 < ET; ++e4)
            xjv[e4] = nf2[(size_t)sDst[et * ET + e4] * 64 + l];

        float as0[ET], as1[ET], ar0[ET], ar1[ET];
        #pragma unroll
        for (int e4 = 0; e4 < ET; ++e4) {
            as0[e4] = bsv.x; as1[e4] = bsv.y;
            ar0[e4] = brv.x; ar1[e4] = brv.y;
        }
        #pragma unroll
        for (int q = 0; q < 4; ++q) {
            uint4 w0q = wt[(0 * 4 + q) * 64];
            uint4 w1q = wt[(1 * 4 + q) * 64];
            uint4 r0q = wt[(2 * 4 + q) * 64];
            uint4 r1q = wt[(3 * 4 + q) * 64];
            #pragma unroll
            for (int e4 = 0; e4 < ET; ++e4) {
                const uint4* hp = reinterpret_cast<const uint4*>(&sH[et * ET + e4][0]);
                uint4 hv = hp[q];       // hs pairs (broadcast)
                uint4 rv = hp[4 + q];   // hr pairs
                as0[e4] = __builtin_amdgcn_fdot2(u2h(hv.x), u2h(w0q.x), as0[e4], false);
                as1[e4] = __builtin_amdgcn_fdot2(u2h(hv.x), u2h(w1q.x), as1[e4], false);
                as0[e4] = __builtin_amdgcn_fdot2(u2h(hv.y), u2h(w0q.y), as0[e4], false);
                as1[e4] = __builtin_amdgcn_fdot2(u2h(hv.y), u2h(w1q.y), as1[e4], false);
                as0[e4] = __builtin_amdgcn_fdot2(u2h(hv.z), u2h(w0q.z), as0[e4], false);
                as1[e4] = __builtin_amdgcn_fdot2(u2h(hv.z), u2h(w1q.z), as1[e4], false);
                as0[e4] = __builtin_amdgcn_fdot2(u2h(hv.w), u2h(w0q.w), as0[e4], false);
                as1[e4] = __builtin_amdgcn_fdot2(u2h(hv.w), u2h(w1q.w), as1[e4], false);
                ar0[e4] = __builtin_amdgcn_fdot2(u2h(rv.x), u2h(r0q.x), ar0[e4], false);
                ar1[e4] = __builtin_amdgcn_fdot2(u2h(rv.x), u2h(r1q.x), ar1[e4], false);
                ar0[e4] = __builtin_amdgcn_fdot2(u2h(rv.y), u2h(r0q.y), ar0[e4], false);
                ar1[e4] = __builtin_amdgcn_fdot2(u2h(rv.y), u2h(r1q.y), ar1[e4], false);
                ar0[e4] = __builtin_amdgcn_fdot2(u2h(rv.z), u2h(r0q.z), ar0[e4], false);
                ar1[e4] = __builtin_amdgcn_fdot2(u2h(rv.z), u2h(r1q.z), ar1[e4], false);
                ar0[e4] = __builtin_amdgcn_fdot2(u2h(rv.w), u2h(r0q.w), ar0[e4], false);
                ar1[e4] = __builtin_amdgcn_fdot2(u2h(rv.w), u2h(r1q.w), ar1[e4], false);
            }
        }
        #pragma unroll
        for (int e4 = 0; e4 < ET; ++e4) {
            int idx = et * ET + e4;
            int src = sSrc[idx];                  // broadcast -> wave-uniform
            if (src != cur) {
                float* ab = g_accu + (size_t)cur * MROW + MOFF + 2 * l;
                #pragma unroll
                for (int k = 0; k < K; ++k) {
                    unsafeAtomicAdd(ab + k * CC,     racc0[k]);
                    unsafeAtomicAdd(ab + k * CC + 1, racc1[k]);
                    racc0[k] = 0.f; racc1[k] = 0.f;
                }
                cur = src;
            }
            float u0 = as0[e4] * ar0[e4] * xjv[e4].x;
            float u1 = as1[e4] * ar1[e4] * xjv[e4].y;
            #pragma unroll
            for (int k = 0; k < K; ++k) {
                float yv = sY[idx][YB + k];
                racc0[k] = fmaf(u0, yv, racc0[k]);
                racc1[k] = fmaf(u1, yv, racc1[k]);
            }
        }
    }
    float* ab = g_accu + (size_t)cur * MROW + MOFF + 2 * l;
    #pragma unroll
    for (int k = 0; k < K; ++k) {
        unsafeAtomicAdd(ab + k * CC,     racc0[k]);
        unsafeAtomicAdd(ab + k * CC + 1, racc1[k]);
    }
}

// Fused edge MLP2 + tensor-product message + segment-sum.
// 192-thr block = 3 waves sharing one 64-edge tile; wave = section.
__global__ __launch_bounds__(192, 4) void fused_kernel(
    const float* __restrict__ nf,
    const float* __restrict__ edge_attr,
    const float* __restrict__ edge_rsh,
    const int*   __restrict__ edge_index,
    const float* __restrict__ bs2,
    const float* __restrict__ Wr1, const float* __restrict__ br1,
    const float* __restrict__ br2)
{
    __shared__ unsigned int sH[EPB][36];   // 9.2 KB packed f16 pairs
    __shared__ float sY[EPB][9];           // 2.3 KB
    __shared__ int   sSrc[EPB], sDst[EPB];

    int tid = threadIdx.x;
    int w = tid / 64;               // wave id = section id
    int l = tid & 63;
    int p = blockIdx.x * EPB + l;   // grid exact: EE/EPB
    int e = g_ord[p];

    if (w == 0) {
        // ---- hs = silu(Pi[s] + Pj[t]) + metadata
        int s = edge_index[e];
        int t = edge_index[EE + e];
        const float4* pi = reinterpret_cast<const float4*>(g_proj + (size_t)s * 64);
        const float4* pj = reinterpret_cast<const float4*>(g_proj + (size_t)t * 64 + HIDD);
        #pragma unroll
        for (int j4 = 0; j4 < HIDD / 8; ++j4) {
            float4 a0 = pi[2 * j4],     b0 = pj[2 * j4];
            float4 a1 = pi[2 * j4 + 1], b1 = pj[2 * j4 + 1];
            sH[l][4 * j4 + 0] = pack_h2(silu_f(a0.x + b0.x), silu_f(a0.y + b0.y));
            sH[l][4 * j4 + 1] = pack_h2(silu_f(a0.z + b0.z), silu_f(a0.w + b0.w));
            sH[l][4 * j4 + 2] = pack_h2(silu_f(a1.x + b1.x), silu_f(a1.y + b1.y));
            sH[l][4 * j4 + 3] = pack_h2(silu_f(a1.z + b1.z), silu_f(a1.w + b1.w));
        }
        sSrc[l] = s;
        sDst[l] = t;
    } else if (w == 1) {
        // ---- hr = silu(edge_attr @ Wr1 + br1)
        float hr[HIDD];
        #pragma unroll
        for (int j = 0; j < HIDD; ++j) hr[j] = br1[j];
        #pragma unroll 1
        for (int k4 = 0; k4 < RBFD / 4; ++k4) {
            float4 a = reinterpret_cast<const float4*>(edge_attr + (size_t)e * RBFD)[k4];
            const float* wp = Wr1 + (4 * k4) * HIDD;
            #pragma unroll
            for (int j = 0; j < HIDD; ++j) {
                hr[j] = fmaf(a.x, wp[j], hr[j]);
                hr[j] = fmaf(a.y, wp[HIDD + j], hr[j]);
                hr[j] = fmaf(a.z, wp[2 * HIDD + j], hr[j]);
                hr[j] = fmaf(a.w, wp[3 * HIDD + j], hr[j]);
            }
        }
        #pragma unroll
        for (int pp = 0; pp < 16; ++pp)
            sH[l][16 + pp] = pack_h2(silu_f(hr[2 * pp]), silu_f(hr[2 * pp + 1]));
    } else {
        // ---- SH coefficients
        #pragma unroll
        for (int i = 0; i < 9; ++i) sY[l][i] = edge_rsh[(size_t)e * 9 + i];
    }
    __syncthreads();

    const float2* nf2 = reinterpret_cast<const float2*>(nf);
    if (w == 0)
        section_pass<1, 0, 0>     (0, l, nf2, bs2, br2, sH, sY, sSrc, sDst);
    else if (w == 1)
        section_pass<3, 1, CC>    (1, l, nf2, bs2, br2, sH, sY, sSrc, sDst);
    else
        section_pass<5, 4, 4 * CC>(2, l, nf2, bs2, br2, sH, sY, sSrc, sDst);
}

// Node-wise linear, 8 nodes per block; re-zeroes g_accu after staging.
__global__ __launch_bounds__(256) void lin2_kernel(
    const float* __restrict__ W0, const float* __restrict__ b0,
    const float* __restrict__ W1, const float* __restrict__ W2,
    float* __restrict__ out)
{
    __shared__ float sA[8 * MROW];   // 36.9 KB
    int n0 = blockIdx.x * 8;         // grid exact: NN/8
    float4* g = reinterpret_cast<float4*>(g_accu + (size_t)n0 * MROW);
    const float4 z4 = make_float4(0.f, 0.f, 0.f, 0.f);
    for (int i = threadIdx.x; i < 8 * MROW / 4; i += 256) {
        float4 v = g[i];
        reinterpret_cast<float4*>(sA)[i] = v;
        g[i] = z4;                   // restore zero for next call
    }
    __syncthreads();

    int d  = threadIdx.x & (CC - 1);
    int nl = threadIdx.x >> 7;       // 0/1 -> nodes nl*4 .. nl*4+3

    float acc[4][9];
    #pragma unroll
    for (int q = 0; q < 4; ++q)
        #pragma unroll
        for (int m = 0; m < 9; ++m) acc[q][m] = 0.f;

    #pragma unroll 1
    for (int c4 = 0; c4 < CC / 4; ++c4) {
        float w0c[4], w1c[4], w2c[4];
        #pragma unroll
        for (int cc = 0; cc < 4; ++cc) {
            int c = 4 * c4 + cc;
            w0c[cc] = W0[c * CC + d];
            w1c[cc] = W1[c * CC + d];
            w2c[cc] = W2[c * CC + d];
        }
        #pragma unroll
        for (int q = 0; q < 4; ++q) {
            const float* a = sA + (size_t)(nl * 4 + q) * MROW + 4 * c4;
            float4 am[9];
            #pragma unroll
            for (int m = 0; m < 9; ++m)
                am[m] = *reinterpret_cast<const float4*>(a + m * CC);
            #pragma unroll
            for (int cc = 0; cc < 4; ++cc) {
                float a0 = (&am[0].x)[cc];
                acc[q][0] = fmaf(a0, w0c[cc], acc[q][0]);
                #pragma unroll
                for (int m = 1; m < 4; ++m)
                    acc[q][m] = fmaf((&am[m].x)[cc], w1c[cc], acc[q][m]);
                #pragma unroll
                for (int m = 4; m < 9; ++m)
                    acc[q][m] = fmaf((&am[m].x)[cc], w2c[cc], acc[q][m]);
            }
        }
    }

    const float inv = 0.08838834764831845f;  // 1/sqrt(128)
    #pragma unroll
    for (int q = 0; q < 4; ++q) {
        size_t ob = (size_t)(n0 + nl * 4 + q) * MROW;
        out[ob + d] = acc[q][0] * inv + b0[d];
        #pragma unroll
        for (int m = 0; m < 3; ++m) out[ob + CC + d * 3 + m]     = acc[q][1 + m] * inv;
        #pragma unroll
        for (int m = 0; m < 5; ++m) out[ob + 4 * CC + d * 5 + m] = acc[q][4 + m] * inv;
    }
}

extern "C" void kernel_launch(void* const* d_in, const int* in_sizes, int n_in,
                              void* d_out, int out_size, void* d_ws, size_t ws_size,
                              hipStream_t stream)
{
    const float* node_feat  = (const float*)d_in[0];
    const float* edge_attr  = (const float*)d_in[1];
    const float* edge_rsh   = (const float*)d_in[2];
    const int*   edge_index = (const int*)  d_in[3];
    const float* Ws1 = (const float*)d_in[4];
    const float* bs1 = (const float*)d_in[5];
    const float* Ws2 = (const float*)d_in[6];
    const float* bs2 = (const float*)d_in[7];
    const float* Wr1 = (const float*)d_in[8];
    const float* br1 = (const float*)d_in[9];
    const float* Wr2 = (const float*)d_in[10];
    const float* br2 = (const float*)d_in[11];
    const float* W0  = (const float*)d_in[12];
    const float* b0  = (const float*)d_in[13];
    const float* W1  = (const float*)d_in[14];
    const float* W2  = (const float*)d_in[15];
    float* out = (float*)d_out;

    pack_kernel<<<1, 192, 0, stream>>>(Ws2, Wr2);      // also zeroes g_deg
    hist_kernel<<<EE / 256, 256, 0, stream>>>(edge_index);
    scan_kernel<<<1, 256, 0, stream>>>();
    proj_kernel<<<NN / 16, 256, 0, stream>>>(node_feat, Ws1, bs1, edge_index);
    fused_kernel<<<EE / EPB, 192, 0, stream>>>(
        node_feat, edge_attr, edge_rsh, edge_index,
        bs2, Wr1, br1, br2);
    lin2_kernel<<<NN / 8, 256, 0, stream>>>(W0, b0, W1, W2, out);
}

// Round 25
// 247.152 us; speedup vs baseline: 4.0102x; 4.0102x over previous
//
#include <hip/hip_runtime.h>
#include <hip/hip_bf16.h>
#include <math.h>

#define NN   10000
#define EE   160000
#define CC   128
#define RBFD 20
#define HIDD 32
#define WND  384
#define MROW 1152   // 9*128 accumulator row: [m=0..8][c=0..127]
#define EPB  64     // edges per block

typedef _Float16 half2_t __attribute__((ext_vector_type(2)));

__device__ __forceinline__ half2_t u2h(unsigned int u)
{
    union { unsigned int u; half2_t h; } c; c.u = u; return c.h;
}
__device__ __forceinline__ unsigned int pack_h2(float a, float b)
{
    union { half2_t h; unsigned int u; } c;
    c.h.x = (_Float16)a; c.h.y = (_Float16)b; return c.u;
}

// Static device buffers. g_accu: starts zero (.bss); each call accumulates,
// lin2 re-zeroes after reading -> invariant "zero at call entry" holds.
__device__ __align__(16) float g_proj[(size_t)NN * 64];   // 2.6 MB
__device__ __align__(16) float g_accu[(size_t)NN * MROW]; // 46 MB
__device__ __align__(16) uint4 g_wp[3 * 16 * 64];         // 48 KB packed f16 weights
__device__ int g_deg[NN];
__device__ int g_offs[NN + 1];
__device__ int g_rel[EE];
__device__ int g_ord[EE];   // sorted row -> original edge

__device__ __forceinline__ float silu_f(float x) { return x / (1.f + __expf(-x)); }

// Pack MLP2 weights to f16 pairs + zero g_deg. Layout [sec][kind][q][lane].
__global__ __launch_bounds__(192) void pack_kernel(
    const float* __restrict__ Ws2, const float* __restrict__ Wr2)
{
    int tid = threadIdx.x;          // 192 = 3 sec x 64 lanes
    for (int i = tid; i < NN; i += 192) g_deg[i] = 0;
    int sec = tid >> 6, l = tid & 63;
    int c0 = sec * 128 + 2 * l;
    #pragma unroll
    for (int q = 0; q < 4; ++q) {
        unsigned int w0[4], w1[4], r0[4], r1[4];
        #pragma unroll
        for (int i = 0; i < 4; ++i) {
            int p = 4 * q + i;
            int b0 = (2 * p) * WND + c0;
            int b1 = (2 * p + 1) * WND + c0;
            w0[i] = pack_h2(Ws2[b0],     Ws2[b1]);
            w1[i] = pack_h2(Ws2[b0 + 1], Ws2[b1 + 1]);
            r0[i] = pack_h2(Wr2[b0],     Wr2[b1]);
            r1[i] = pack_h2(Wr2[b0 + 1], Wr2[b1 + 1]);
        }
        g_wp[((sec * 16 + 0 * 4 + q) * 64) + l] = make_uint4(w0[0], w0[1], w0[2], w0[3]);
        g_wp[((sec * 16 + 1 * 4 + q) * 64) + l] = make_uint4(w1[0], w1[1], w1[2], w1[3]);
        g_wp[((sec * 16 + 2 * 4 + q) * 64) + l] = make_uint4(r0[0], r0[1], r0[2], r0[3]);
        g_wp[((sec * 16 + 3 * 4 + q) * 64) + l] = make_uint4(r1[0], r1[1], r1[2], r1[3]);
    }
}

__global__ __launch_bounds__(256) void hist_kernel(const int* __restrict__ edge_index)
{
    int e = blockIdx.x * 256 + threadIdx.x;
    if (e < EE) g_rel[e] = atomicAdd(&g_deg[edge_index[e]], 1);
}

// Blocked scan: 256 threads x 40 items, one block.
__global__ __launch_bounds__(256) void scan_kernel()
{
    __shared__ int sP[256];
    int t = threadIdx.x;
    int lo = t * 40, hi = min(lo + 40, NN);
    int sum = 0;
    for (int i = lo; i < hi; ++i) sum += g_deg[i];
    sP[t] = sum;
    __syncthreads();
    for (int off = 1; off < 256; off <<= 1) {
        int v = (t >= off) ? sP[t - off] : 0;
        __syncthreads();
        sP[t] += v;
        __syncthreads();
    }
    int run = sP[t] - sum;   // exclusive prefix
    if (t == 0) g_offs[0] = 0;
    for (int i = lo; i < hi; ++i) { run += g_deg[i]; g_offs[i + 1] = run; }
}

// MLP1 halves + edge permutation (grid is exactly EE threads).
__global__ __launch_bounds__(256) void proj_kernel(
    const float* __restrict__ nf,
    const float* __restrict__ Ws1, const float* __restrict__ bs1,
    const int* __restrict__ edge_index)
{
    __shared__ float sX[16][132];

    int tid = threadIdx.x;
    int nb = blockIdx.x * 16;       // grid exact: NN/16 = 625

    {
        int eg = blockIdx.x * 256 + tid;
        g_ord[g_offs[edge_index[eg]] + g_rel[eg]] = eg;
    }

    #pragma unroll
    for (int i = tid; i < 512; i += 256) {
        int n = i >> 5, k4 = i & 31;
        float4 v = reinterpret_cast<const float4*>(nf + (size_t)(nb + n) * CC)[k4];
        sX[n][k4 * 4 + 0] = v.x;
        sX[n][k4 * 4 + 1] = v.y;
        sX[n][k4 * 4 + 2] = v.z;
        sX[n][k4 * 4 + 3] = v.w;
    }
    __syncthreads();

    int nl = tid >> 4;
    int qd = tid & 15;
    int j0 = (qd & 7) * 4;
    int rbase = (qd >= 8) ? CC : 0;

    float4 acc;
    if (qd < 8) acc = *reinterpret_cast<const float4*>(&bs1[j0]);
    else        acc = make_float4(0.f, 0.f, 0.f, 0.f);

    const float* wb = Ws1 + (size_t)rbase * HIDD + j0;
    #pragma unroll 4
    for (int k = 0; k < CC; ++k) {
        float f = sX[nl][k];
        float4 w = *reinterpret_cast<const float4*>(wb + (size_t)k * HIDD);
        acc.x = fmaf(f, w.x, acc.x);
        acc.y = fmaf(f, w.y, acc.y);
        acc.z = fmaf(f, w.z, acc.z);
        acc.w = fmaf(f, w.w, acc.w);
    }

    float* o = g_proj + (size_t)(nb + nl) * 64 + ((qd >= 8) ? HIDD : 0) + j0;
    *reinterpret_cast<float4*>(o) = acc;
}

// One 128-col section over EPB sorted edges: lane owns cols (2l, 2l+1);
// pre-packed f16 weights (16 coalesced b128 from 48KB L1-resident table, no
// cvt); h via broadcast b128 from LDS; per-segment register accumulation;
// wave-coalesced atomic flushes. (R23 structure: only shape that stays
// within the allocator's ~60-VGPR envelope without spilling.)
template<int K, int YB, int MOFF>
__device__ __forceinline__ void section_pass(
    int sec, int l,
    const float2* __restrict__ nf2,
    const float* __restrict__ bs2, const float* __restrict__ br2,
    const unsigned int (*__restrict__ sH)[36], const float (*__restrict__ sY)[9],
    const int* __restrict__ sSrc, const int* __restrict__ sDst)
{
    const uint4* wt = g_wp + (size_t)sec * 16 * 64 + l;   // stride 64 per slot
    uint4 W0q[4], W1q[4], R0q[4], R1q[4];
    #pragma unroll
    for (int q = 0; q < 4; ++q) {
        W0q[q] = wt[(0 * 4 + q) * 64];
        W1q[q] = wt[(1 * 4 + q) * 64];
        R0q[q] = wt[(2 * 4 + q) * 64];
        R1q[q] = wt[(3 * 4 + q) * 64];
    }

    float2 bsv = *reinterpret_cast<const float2*>(&bs2[sec * 128 + 2 * l]);
    float2 brv = *reinterpret_cast<const float2*>(&br2[sec * 128 + 2 * l]);

    float racc0[K], racc1[K];
    #pragma unroll
    for (int k = 0; k < K; ++k) { racc0[k] = 0.f; racc1[k] = 0.f; }
    int cur = sSrc[0];
    float2 xjn = nf2[(size_t)sDst[0] * 64 + l];

    #pragma unroll 2
    for (int ee = 0; ee < EPB; ++ee) {
        int src = sSrc[ee];                       // broadcast -> wave-uniform
        if (src != cur) {
            float* ab = g_accu + (size_t)cur * MROW + MOFF + 2 * l;
            #pragma unroll
            for (int k = 0; k < K; ++k) {
                unsafeAtomicAdd(ab + k * CC,     racc0[k]);
                unsafeAtomicAdd(ab + k * CC + 1, racc1[k]);
                racc0[k] = 0.f; racc1[k] = 0.f;
            }
            cur = src;
        }
        float2 xj = xjn;
        xjn = nf2[(size_t)sDst[(ee + 1) & (EPB - 1)] * 64 + l];   // prefetch next
        const uint4* hp = reinterpret_cast<const uint4*>(&sH[ee][0]);
        float as0 = bsv.x, as1 = bsv.y, ar0 = brv.x, ar1 = brv.y;
        #pragma unroll
        for (int q = 0; q < 4; ++q) {
            uint4 hv = hp[q];       // hs pairs (broadcast)
            uint4 rv = hp[4 + q];   // hr pairs
            as0 = __builtin_amdgcn_fdot2(u2h(hv.x), u2h(W0q[q].x), as0, false);
            as1 = __builtin_amdgcn_fdot2(u2h(hv.x), u2h(W1q[q].x), as1, false);
            as0 = __builtin_amdgcn_fdot2(u2h(hv.y), u2h(W0q[q].y), as0, false);
            as1 = __builtin_amdgcn_fdot2(u2h(hv.y), u2h(W1q[q].y), as1, false);
            as0 = __builtin_amdgcn_fdot2(u2h(hv.z), u2h(W0q[q].z), as0, false);
            as1 = __builtin_amdgcn_fdot2(u2h(hv.z), u2h(W1q[q].z), as1, false);
            as0 = __builtin_amdgcn_fdot2(u2h(hv.w), u2h(W0q[q].w), as0, false);
            as1 = __builtin_amdgcn_fdot2(u2h(hv.w), u2h(W1q[q].w), as1, false);
            ar0 = __builtin_amdgcn_fdot2(u2h(rv.x), u2h(R0q[q].x), ar0, false);
            ar1 = __builtin_amdgcn_fdot2(u2h(rv.x), u2h(R1q[q].x), ar1, false);
            ar0 = __builtin_amdgcn_fdot2(u2h(rv.y), u2h(R0q[q].y), ar0, false);
            ar1 = __builtin_amdgcn_fdot2(u2h(rv.y), u2h(R1q[q].y), ar1, false);
            ar0 = __builtin_amdgcn_fdot2(u2h(rv.z), u2h(R0q[q].z), ar0, false);
            ar1 = __builtin_amdgcn_fdot2(u2h(rv.z), u2h(R1q[q].z), ar1, false);
            ar0 = __builtin_amdgcn_fdot2(u2h(rv.w), u2h(R0q[q].w), ar0, false);
            ar1 = __builtin_amdgcn_fdot2(u2h(rv.w), u2h(R1q[q].w), ar1, false);
        }
        float u0 = as0 * ar0 * xj.x;
        float u1 = as1 * ar1 * xj.y;
        #pragma unroll
        for (int k = 0; k < K; ++k) {
            float yv = sY[ee][YB + k];
            racc0[k] = fmaf(u0, yv, racc0[k]);
            racc1[k] = fmaf(u1, yv, racc1[k]);
        }
    }
    float* ab = g_accu + (size_t)cur * MROW + MOFF + 2 * l;
    #pragma unroll
    for (int k = 0; k < K; ++k) {
        unsafeAtomicAdd(ab + k * CC,     racc0[k]);
        unsafeAtomicAdd(ab + k * CC + 1, racc1[k]);
    }
}

// Fused edge MLP2 + tensor-product message + segment-sum.
// 192-thr block = 3 waves sharing one 64-edge tile; wave = section.
__global__ __launch_bounds__(192, 4) void fused_kernel(
    const float* __restrict__ nf,
    const float* __restrict__ edge_attr,
    const float* __restrict__ edge_rsh,
    const int*   __restrict__ edge_index,
    const float* __restrict__ bs2,
    const float* __restrict__ Wr1, const float* __restrict__ br1,
    const float* __restrict__ br2)
{
    __shared__ unsigned int sH[EPB][36];   // 9.2 KB packed f16 pairs
    __shared__ float sY[EPB][9];           // 2.3 KB
    __shared__ int   sSrc[EPB], sDst[EPB];

    int tid = threadIdx.x;
    int w = tid / 64;               // wave id = section id
    int l = tid & 63;
    int p = blockIdx.x * EPB + l;   // grid exact: EE/EPB
    int e = g_ord[p];

    if (w == 0) {
        // ---- hs = silu(Pi[s] + Pj[t]) + metadata
        int s = edge_index[e];
        int t = edge_index[EE + e];
        const float4* pi = reinterpret_cast<const float4*>(g_proj + (size_t)s * 64);
        const float4* pj = reinterpret_cast<const float4*>(g_proj + (size_t)t * 64 + HIDD);
        #pragma unroll
        for (int j4 = 0; j4 < HIDD / 8; ++j4) {
            float4 a0 = pi[2 * j4],     b0 = pj[2 * j4];
            float4 a1 = pi[2 * j4 + 1], b1 = pj[2 * j4 + 1];
            sH[l][4 * j4 + 0] = pack_h2(silu_f(a0.x + b0.x), silu_f(a0.y + b0.y));
            sH[l][4 * j4 + 1] = pack_h2(silu_f(a0.z + b0.z), silu_f(a0.w + b0.w));
            sH[l][4 * j4 + 2] = pack_h2(silu_f(a1.x + b1.x), silu_f(a1.y + b1.y));
            sH[l][4 * j4 + 3] = pack_h2(silu_f(a1.z + b1.z), silu_f(a1.w + b1.w));
        }
        sSrc[l] = s;
        sDst[l] = t;
    } else if (w == 1) {
        // ---- hr = silu(edge_attr @ Wr1 + br1)
        float hr[HIDD];
        #pragma unroll
        for (int j = 0; j < HIDD; ++j) hr[j] = br1[j];
        #pragma unroll 1
        for (int k4 = 0; k4 < RBFD / 4; ++k4) {
            float4 a = reinterpret_cast<const float4*>(edge_attr + (size_t)e * RBFD)[k4];
            const float* wp = Wr1 + (4 * k4) * HIDD;
            #pragma unroll
            for (int j = 0; j < HIDD; ++j) {
                hr[j] = fmaf(a.x, wp[j], hr[j]);
                hr[j] = fmaf(a.y, wp[HIDD + j], hr[j]);
                hr[j] = fmaf(a.z, wp[2 * HIDD + j], hr[j]);
                hr[j] = fmaf(a.w, wp[3 * HIDD + j], hr[j]);
            }
        }
        #pragma unroll
        for (int pp = 0; pp < 16; ++pp)
            sH[l][16 + pp] = pack_h2(silu_f(hr[2 * pp]), silu_f(hr[2 * pp + 1]));
    } else {
        // ---- SH coefficients
        #pragma unroll
        for (int i = 0; i < 9; ++i) sY[l][i] = edge_rsh[(size_t)e * 9 + i];
    }
    __syncthreads();

    const float2* nf2 = reinterpret_cast<const float2*>(nf);
    if (w == 0)
        section_pass<1, 0, 0>     (0, l, nf2, bs2, br2, sH, sY, sSrc, sDst);
    else if (w == 1)
        section_pass<3, 1, CC>    (1, l, nf2, bs2, br2, sH, sY, sSrc, sDst);
    else
        section_pass<5, 4, 4 * CC>(2, l, nf2, bs2, br2, sH, sY, sSrc, sDst);
}

// Node-wise linear, 8 nodes per block; re-zeroes g_accu after staging.
__global__ __launch_bounds__(256) void lin2_kernel(
    const float* __restrict__ W0, const float* __restrict__ b0,
    const float* __restrict__ W1, const float* __restrict__ W2,
    float* __restrict__ out)
{
    __shared__ float sA[8 * MROW];   // 36.9 KB
    int n0 = blockIdx.x * 8;         // grid exact: NN/8
    float4* g = reinterpret_cast<float4*>(g_accu + (size_t)n0 * MROW);
    const float4 z4 = make_float4(0.f, 0.f, 0.f, 0.f);
    for (int i = threadIdx.x; i < 8 * MROW / 4; i += 256) {
        float4 v = g[i];
        reinterpret_cast<float4*>(sA)[i] = v;
        g[i] = z4;                   // restore zero for next call
    }
    __syncthreads();

    int d  = threadIdx.x & (CC - 1);
    int nl = threadIdx.x >> 7;       // 0/1 -> nodes nl*4 .. nl*4+3

    float acc[4][9];
    #pragma unroll
    for (int q = 0; q < 4; ++q)
        #pragma unroll
        for (int m = 0; m < 9; ++m) acc[q][m] = 0.f;

    #pragma unroll 1
    for (int c4 = 0; c4 < CC / 4; ++c4) {
        float w0c[4], w1c[4], w2c[4];
        #pragma unroll
        for (int cc = 0; cc < 4; ++cc) {
            int c = 4 * c4 + cc;
            w0c[cc] = W0[c * CC + d];
            w1c[cc] = W1[c * CC + d];
            w2c[cc] = W2[c * CC + d];
        }
        #pragma unroll
        for (int q = 0; q < 4; ++q) {
            const float* a = sA + (size_t)(nl * 4 + q) * MROW + 4 * c4;
            float4 am[9];
            #pragma unroll
            for (int m = 0; m < 9; ++m)
                am[m] = *reinterpret_cast<const float4*>(a + m * CC);
            #pragma unroll
            for (int cc = 0; cc < 4; ++cc) {
                acc[q][0] = fmaf((&am[0].x)[cc], w0c[cc], acc[q][0]);
                #pragma unroll
                for (int m = 1; m < 4; ++m)
                    acc[q][m] = fmaf((&am[m].x)[cc], w1c[cc], acc[q][m]);
                #pragma unroll
                for (int m = 4; m < 9; ++m)
                    acc[q][m] = fmaf((&am[m].x)[cc], w2c[cc], acc[q][m]);
            }
        }
    }

    const float inv = 0.08838834764831845f;  // 1/sqrt(128)
    #pragma unroll
    for (int q = 0; q < 4; ++q) {
        size_t ob = (size_t)(n0 + nl * 4 + q) * MROW;
        out[ob + d] = acc[q][0] * inv + b0[d];
        #pragma unroll
        for (int m = 0; m < 3; ++m) out[ob + CC + d * 3 + m]     = acc[q][1 + m] * inv;
        #pragma unroll
        for (int m = 0; m < 5; ++m) out[ob + 4 * CC + d * 5 + m] = acc[q][4 + m] * inv;
    }
}

extern "C" void kernel_launch(void* const* d_in, const int* in_sizes, int n_in,
                              void* d_out, int out_size, void* d_ws, size_t ws_size,
                              hipStream_t stream)
{
    const float* node_feat  = (const float*)d_in[0];
    const float* edge_attr  = (const float*)d_in[1];
    const float* edge_rsh   = (const float*)d_in[2];
    const int*   edge_index = (const int*)  d_in[3];
    const float* Ws1 = (const float*)d_in[4];
    const float* bs1 = (const float*)d_in[5];
    const float* Ws2 = (const float*)d_in[6];
    const float* bs2 = (const float*)d_in[7];
    const float* Wr1 = (const float*)d_in[8];
    const float* br1 = (const float*)d_in[9];
    const float* Wr2 = (const float*)d_in[10];
    const float* br2 = (const float*)d_in[11];
    const float* W0  = (const float*)d_in[12];
    const float* b0  = (const float*)d_in[13];
    const float* W1  = (const float*)d_in[14];
    const float* W2  = (const float*)d_in[15];
    float* out = (float*)d_out;

    pack_kernel<<<1, 192, 0, stream>>>(Ws2, Wr2);      // also zeroes g_deg
    hist_kernel<<<EE / 256, 256, 0, stream>>>(edge_index);
    scan_kernel<<<1, 256, 0, stream>>>();
    proj_kernel<<<NN / 16, 256, 0, stream>>>(node_feat, Ws1, bs1, edge_index);
    fused_kernel<<<EE / EPB, 192, 0, stream>>>(
        node_feat, edge_attr, edge_rsh, edge_index,
        bs2, Wr1, br1, br2);
    lin2_kernel<<<NN / 8, 256, 0, stream>>>(W0, b0, W1, W2, out);
}